// Round 6
// baseline (226.404 us; speedup 1.0000x reference)
//
#include <hip/hip_runtime.h>
#include <hip/hip_fp16.h>

#define BHW   25088
#define HW    3136
#define DD    64
#define KNEG  100
#define NBLK2 (BHW / 4)   // 6272 blocks, 4 waves (n's) per block

typedef float v2f __attribute__((ext_vector_type(2)));

#if __has_builtin(__builtin_amdgcn_cvt_pk_f32_fp8) && __has_builtin(__builtin_amdgcn_cvt_pk_fp8_f32)
#define HAVE_FP8CVT 1
#else
#define HAVE_FP8CVT 0
#endif

// ---- fp8 e4m3fn encode/decode (HW cvt on gfx950; SW fallback) -------------
__device__ __forceinline__ uint32_t enc4(float a, float b, float c, float d) {
#if HAVE_FP8CVT
    int u = __builtin_amdgcn_cvt_pk_fp8_f32(a, b, 0, false);
    u = __builtin_amdgcn_cvt_pk_fp8_f32(c, d, u, true);
    return (uint32_t)u;
#else
    auto enc1 = [](float x) -> uint32_t {
        float ax = fabsf(x);
        uint32_t s = (__float_as_uint(x) >> 31) << 7;
        if (ax < 0x1p-10f) return s;
        int e; float m = frexpf(ax, &e);          // ax = m*2^e, m in [0.5,1)
        if (e >= -5) {
            int mant = (int)rintf(m * 16.f);      // 8..16
            if (mant == 16) { mant = 8; e += 1; }
            if (e > 8) return s | 0x7e;           // clamp to max finite
            return s | ((uint32_t)(e + 6) << 3) | (uint32_t)(mant - 8);
        }
        int q = (int)rintf(ax * 512.f);           // denormal grid 2^-9
        if (q >= 8) return s | (1u << 3);
        return s | (uint32_t)q;
    };
    return enc1(a) | (enc1(b) << 8) | (enc1(c) << 16) | (enc1(d) << 24);
#endif
}

__device__ __forceinline__ void dec4(uint32_t u, float* f) {
#if HAVE_FP8CVT
    v2f p0 = __builtin_amdgcn_cvt_pk_f32_fp8((int)u, false);
    v2f p1 = __builtin_amdgcn_cvt_pk_f32_fp8((int)u, true);
    f[0] = p0.x; f[1] = p0.y; f[2] = p1.x; f[3] = p1.y;
#else
    for (int i = 0; i < 4; ++i) {
        uint32_t b = (u >> (8 * i)) & 0xff;
        uint32_t s = b >> 7, e = (b >> 3) & 15, m = b & 7;
        float v = e ? __uint_as_float(((e + 120u) << 23) | (m << 20))
                    : (float)m * 0x1p-9f;
        f[i] = s ? -v : v;
    }
#endif
}

// ---------------------------------------------------------------------------
// Kernel 1 (512 thr): normalize x1 rows -> xq (fp8 e4m3, row-major (n,64)),
// positive[n] in f32. LDS tile-transpose; 8 waves/block. Block 0 also zeroes
// the sum/cnt cells used by k2's fused finalize (ws is 0xAA-poisoned every
// replay; kernel-boundary coherence makes the zeros visible to k2).
// ---------------------------------------------------------------------------
__global__ __launch_bounds__(512) void k1_normalize(
    const float* __restrict__ x1, const float* __restrict__ x2,
    uint32_t* __restrict__ xq, float* __restrict__ pos,
    float* __restrict__ sum, int* __restrict__ cnt)
{
    __shared__ float A[64][65];   // +1 pad
    __shared__ float C[64][65];
    __shared__ float inv1[64];

    const int t   = threadIdx.x;
    const int col = t & 63;       // hw within tile
    const int qr  = t >> 6;       // wave id 0..7
    const int b    = blockIdx.x / 49;
    const int tile = blockIdx.x % 49;
    const int hw0  = tile * 64;

    if (blockIdx.x == 0 && t == 0) { *sum = 0.f; *cnt = 0; }

    const float* p1 = x1 + (size_t)b * DD * HW + hw0;
    const float* p2 = x2 + (size_t)b * DD * HW + hw0;

#pragma unroll
    for (int i = 0; i < 8; ++i) {
        const int row = i * 8 + qr;                  // d index
        A[row][col] = __builtin_nontemporal_load(&p1[(size_t)row * HW + col]);
        C[row][col] = __builtin_nontemporal_load(&p2[(size_t)row * HW + col]);
    }
    __syncthreads();

    // phase 2: 512 threads = 64 rows x 8 d-chunks of 8 (8 lanes per row)
    const int l   = t & 63;
    const int r   = qr * 8 + (l >> 3);  // row (hw) within tile
    const int sub = l & 7;              // d-chunk 0..7

    float na = 0.f, nc = 0.f;
#pragma unroll
    for (int j = 0; j < 8; ++j) {
        const int d = sub * 8 + j;
        const float a = A[d][r], cc = C[d][r];
        na += a * a;
        nc += cc * cc;
    }
    na += __shfl_xor(na, 1); na += __shfl_xor(na, 2); na += __shfl_xor(na, 4);
    nc += __shfl_xor(nc, 1); nc += __shfl_xor(nc, 2); nc += __shfl_xor(nc, 4);
    const float r1 = 1.0f / fmaxf(sqrtf(na), 1e-12f);
    const float rc = 1.0f / fmaxf(sqrtf(nc), 1e-12f);
    const float scale = r1 * rc;

    float p = 0.f;
#pragma unroll
    for (int j = 0; j < 8; ++j) {
        const int d = sub * 8 + j;
        p += __expf(A[d][r] * C[d][r] * scale);   // TEMP == 1
    }
    p += __shfl_xor(p, 1); p += __shfl_xor(p, 2); p += __shfl_xor(p, 4);

    if (sub == 0) {
        pos[b * HW + hw0 + r] = p;
        inv1[r] = r1;
    }
    __syncthreads();

    // phase 3: write fp8 table row-major: 64 rows x 16 uint (4 fp8 each).
    uint32_t* outb = xq + (size_t)(b * HW + hw0) * 16;
    const int cp     = t & 15;    // uint index -> d = 4cp..4cp+3
    const int rowsel = t >> 4;    // 0..31
#pragma unroll
    for (int i = 0; i < 2; ++i) {
        const int nl = i * 32 + rowsel;
        const float s = inv1[nl];
        outb[(size_t)nl * 16 + cp] =
            enc4(A[4 * cp + 0][nl] * s, A[4 * cp + 1][nl] * s,
                 A[4 * cp + 2][nl] * s, A[4 * cp + 3][nl] * s);
    }
}

// ---------------------------------------------------------------------------
// Kernel 2: negative[n] = sum_k exp(dot64(xq[n], xq[idx[n,k]])) + fused
// finalize. One wave per n; 4 lanes per negative (g=l>>2), lane c=l&3 reads
// one uint4 (16 fp8 = quarter row); each gathered row = exactly one 64B line.
// Table 1.6MB -> L2-resident per XCD.
// Finalize: device-scope atomicAdd only (executes at the coherent point, NO
// acq/rel fences -> no buffer_inv/wbl2 -> L2 table stays resident; the R3
// regression came from the fences, not the atomics). Explicit vmcnt(0) wait
// orders each block's sum-add before its cnt-add, so the last incrementer
// observes the complete sum.
// ---------------------------------------------------------------------------
__device__ __forceinline__ float neg_term(const uint4* __restrict__ gp,
                                          int row, int c,
                                          const float* __restrict__ qf)
{
    const uint4 v = gp[(size_t)row * 4 + c];
    float kf[16];
    dec4(v.x, kf + 0); dec4(v.y, kf + 4);
    dec4(v.z, kf + 8); dec4(v.w, kf + 12);
    float s0 = 0.f, s1 = 0.f;
#pragma unroll
    for (int j = 0; j < 8; ++j) {
        s0 = fmaf(kf[2 * j + 0], qf[2 * j + 0], s0);
        s1 = fmaf(kf[2 * j + 1], qf[2 * j + 1], s1);
    }
    float s = s0 + s1;
    s += __shfl_xor(s, 1);
    s += __shfl_xor(s, 2);     // 4-lane group holds full dot
    return __expf(s);          // TEMP == 1
}

__global__ __launch_bounds__(256) void k2_negative(
    const uint32_t* __restrict__ xq, const int* __restrict__ neg_idx,
    const float* __restrict__ pos, float* __restrict__ sum,
    int* __restrict__ cnt, float* __restrict__ out)
{
    __shared__ float wpart[4];

    const int t = threadIdx.x;
    const int w = t >> 6;         // wave id 0..3
    const int l = t & 63;
    const int n = blockIdx.x * 4 + w;
    const int g = l >> 2;         // negative group 0..15
    const int c = l & 3;          // 16B slot within 64B row

    const uint4* gp = (const uint4*)xq;   // 4 x uint4 per row
    const int* idxp = neg_idx + (size_t)n * KNEG;

    // query fragment: d in [16c, 16c+16) of row n, decoded once to f32
    const uint4 qw = gp[(size_t)n * 4 + c];
    float qf[16];
    dec4(qw.x, qf + 0); dec4(qw.y, qf + 4);
    dec4(qw.z, qf + 8); dec4(qw.w, qf + 12);

    float acc = 0.f;
#pragma unroll
    for (int i = 0; i < 6; ++i) {
        acc += neg_term(gp, idxp[i * 16 + g], c, qf);   // k = i*16+g
    }
    if (g < 4) {                                        // k = 96..99
        acc += neg_term(gp, idxp[96 + g], c, qf);
    }
    // lanes within a group hold identical acc; butterfly across 16 groups
    acc += __shfl_xor(acc, 4);
    acc += __shfl_xor(acc, 8);
    acc += __shfl_xor(acc, 16);
    acc += __shfl_xor(acc, 32);

    if (l == 0) wpart[w] = log1pf(acc / pos[n]);   // log(p+neg)-log(p)
    __syncthreads();

    if (t == 0) {
        const float bsum = wpart[0] + wpart[1] + wpart[2] + wpart[3];
        atomicAdd(sum, bsum);                       // device scope, no fence
        __asm__ __volatile__("s_waitcnt vmcnt(0)" ::: "memory");
        const int prev = atomicAdd(cnt, 1);
        if (prev == NBLK2 - 1) {
            const float total = atomicAdd(sum, 0.0f);  // read at coherent point
            out[0] = total * (1.0f / (float)BHW);
        }
    }
}

extern "C" void kernel_launch(void* const* d_in, const int* in_sizes, int n_in,
                              void* d_out, int out_size, void* d_ws, size_t ws_size,
                              hipStream_t stream)
{
    const float* x1  = (const float*)d_in[0];
    const float* x2  = (const float*)d_in[1];
    const int*   neg = (const int*)d_in[2];
    float* out = (float*)d_out;

    char* ws = (char*)d_ws;
    uint32_t* xq = (uint32_t*)ws;                            // 25088*64 fp8 = 1.61 MB
    float* pos   = (float*)(ws + (size_t)BHW * DD);          // 25088 f32
    float* sum   = (float*)(ws + (size_t)BHW * DD + BHW * 4);
    int*   cnt   = (int*)  (ws + (size_t)BHW * DD + BHW * 4 + 4);

    k1_normalize<<<8 * 49, 512, 0, stream>>>(x1, x2, xq, pos, sum, cnt);
    k2_negative<<<NBLK2, 256, 0, stream>>>(xq, neg, pos, sum, cnt, out);
}

// Round 7
// 98.464 us; speedup vs baseline: 2.2994x; 2.2994x over previous
//
#include <hip/hip_runtime.h>
#include <hip/hip_fp16.h>

#define BHW   25088
#define HW    3136
#define DD    64
#define KNEG  100
#define NBLK2 (BHW / 4)   // 6272 blocks, 4 waves (n's) per block

typedef float v2f __attribute__((ext_vector_type(2)));

#if __has_builtin(__builtin_amdgcn_cvt_pk_f32_fp8) && __has_builtin(__builtin_amdgcn_cvt_pk_fp8_f32)
#define HAVE_FP8CVT 1
#else
#define HAVE_FP8CVT 0
#endif

// ---- fp8 e4m3fn encode/decode (HW cvt on gfx950; SW fallback) -------------
__device__ __forceinline__ uint32_t enc4(float a, float b, float c, float d) {
#if HAVE_FP8CVT
    int u = __builtin_amdgcn_cvt_pk_fp8_f32(a, b, 0, false);
    u = __builtin_amdgcn_cvt_pk_fp8_f32(c, d, u, true);
    return (uint32_t)u;
#else
    auto enc1 = [](float x) -> uint32_t {
        float ax = fabsf(x);
        uint32_t s = (__float_as_uint(x) >> 31) << 7;
        if (ax < 0x1p-10f) return s;
        int e; float m = frexpf(ax, &e);          // ax = m*2^e, m in [0.5,1)
        if (e >= -5) {
            int mant = (int)rintf(m * 16.f);      // 8..16
            if (mant == 16) { mant = 8; e += 1; }
            if (e > 8) return s | 0x7e;           // clamp to max finite
            return s | ((uint32_t)(e + 6) << 3) | (uint32_t)(mant - 8);
        }
        int q = (int)rintf(ax * 512.f);           // denormal grid 2^-9
        if (q >= 8) return s | (1u << 3);
        return s | (uint32_t)q;
    };
    return enc1(a) | (enc1(b) << 8) | (enc1(c) << 16) | (enc1(d) << 24);
#endif
}

__device__ __forceinline__ void dec4(uint32_t u, float* f) {
#if HAVE_FP8CVT
    v2f p0 = __builtin_amdgcn_cvt_pk_f32_fp8((int)u, false);
    v2f p1 = __builtin_amdgcn_cvt_pk_f32_fp8((int)u, true);
    f[0] = p0.x; f[1] = p0.y; f[2] = p1.x; f[3] = p1.y;
#else
    for (int i = 0; i < 4; ++i) {
        uint32_t b = (u >> (8 * i)) & 0xff;
        uint32_t s = b >> 7, e = (b >> 3) & 15, m = b & 7;
        float v = e ? __uint_as_float(((e + 120u) << 23) | (m << 20))
                    : (float)m * 0x1p-9f;
        f[i] = s ? -v : v;
    }
#endif
}

// ---------------------------------------------------------------------------
// Kernel 1 (512 thr): normalize x1 rows -> xq (fp8 e4m3, row-major (n,64)),
// positive[n] in f32. LDS tile-transpose; 8 waves/block. Nontemporal input
// loads (single-use stream; keep L2 clean for the xq table).
// ---------------------------------------------------------------------------
__global__ __launch_bounds__(512) void k1_normalize(
    const float* __restrict__ x1, const float* __restrict__ x2,
    uint32_t* __restrict__ xq, float* __restrict__ pos)
{
    __shared__ float A[64][65];   // +1 pad
    __shared__ float C[64][65];
    __shared__ float inv1[64];

    const int t   = threadIdx.x;
    const int col = t & 63;       // hw within tile
    const int qr  = t >> 6;       // wave id 0..7
    const int b    = blockIdx.x / 49;
    const int tile = blockIdx.x % 49;
    const int hw0  = tile * 64;

    const float* p1 = x1 + (size_t)b * DD * HW + hw0;
    const float* p2 = x2 + (size_t)b * DD * HW + hw0;

#pragma unroll
    for (int i = 0; i < 8; ++i) {
        const int row = i * 8 + qr;                  // d index
        A[row][col] = __builtin_nontemporal_load(&p1[(size_t)row * HW + col]);
        C[row][col] = __builtin_nontemporal_load(&p2[(size_t)row * HW + col]);
    }
    __syncthreads();

    // phase 2: 512 threads = 64 rows x 8 d-chunks of 8 (8 lanes per row)
    const int l   = t & 63;
    const int r   = qr * 8 + (l >> 3);  // row (hw) within tile
    const int sub = l & 7;              // d-chunk 0..7

    float na = 0.f, nc = 0.f;
#pragma unroll
    for (int j = 0; j < 8; ++j) {
        const int d = sub * 8 + j;
        const float a = A[d][r], cc = C[d][r];
        na += a * a;
        nc += cc * cc;
    }
    na += __shfl_xor(na, 1); na += __shfl_xor(na, 2); na += __shfl_xor(na, 4);
    nc += __shfl_xor(nc, 1); nc += __shfl_xor(nc, 2); nc += __shfl_xor(nc, 4);
    const float r1 = 1.0f / fmaxf(sqrtf(na), 1e-12f);
    const float rc = 1.0f / fmaxf(sqrtf(nc), 1e-12f);
    const float scale = r1 * rc;

    float p = 0.f;
#pragma unroll
    for (int j = 0; j < 8; ++j) {
        const int d = sub * 8 + j;
        p += __expf(A[d][r] * C[d][r] * scale);   // TEMP == 1
    }
    p += __shfl_xor(p, 1); p += __shfl_xor(p, 2); p += __shfl_xor(p, 4);

    if (sub == 0) {
        pos[b * HW + hw0 + r] = p;
        inv1[r] = r1;
    }
    __syncthreads();

    // phase 3: write fp8 table row-major: 64 rows x 16 uint (4 fp8 each).
    uint32_t* outb = xq + (size_t)(b * HW + hw0) * 16;
    const int cp     = t & 15;    // uint index -> d = 4cp..4cp+3
    const int rowsel = t >> 4;    // 0..31
#pragma unroll
    for (int i = 0; i < 2; ++i) {
        const int nl = i * 32 + rowsel;
        const float s = inv1[nl];
        outb[(size_t)nl * 16 + cp] =
            enc4(A[4 * cp + 0][nl] * s, A[4 * cp + 1][nl] * s,
                 A[4 * cp + 2][nl] * s, A[4 * cp + 3][nl] * s);
    }
}

// ---------------------------------------------------------------------------
// Kernel 2: negative[n] = sum_k exp(dot64(xq[n], xq[idx[n,k]])).
// One wave per n; 4 lanes per negative (g=l>>2), lane c=l&3 reads one uint4
// (16 fp8 = quarter row); each gathered row = exactly one 64B line.
// Table 1.6MB -> fully L2-resident per XCD.
// MLP restructure: all 7 idx loads, then ALL 7 gather dwordx4 issued
// back-to-back into a register array (7 loads in flight per wave), then all
// compute. Uniform clamp+mask tail (no divergent branch).
// NO fences (R3: acq/rel flushes per-XCD L2) and NO grid-wide same-address
// atomics (R6: serialized coherent-point RMW, ~150us for 12.5k ops).
// ---------------------------------------------------------------------------
__global__ __launch_bounds__(256) void k2_negative(
    const uint32_t* __restrict__ xq, const int* __restrict__ neg_idx,
    const float* __restrict__ pos, float* __restrict__ partials)
{
    __shared__ float wpart[4];

    const int t = threadIdx.x;
    const int w = t >> 6;         // wave id 0..3
    const int l = t & 63;
    const int n = blockIdx.x * 4 + w;
    const int g = l >> 2;         // negative group 0..15
    const int c = l & 3;          // 16B slot within 64B row

    const uint4* gp = (const uint4*)xq;   // 4 x uint4 per row
    const int* idxp = neg_idx + (size_t)n * KNEG;

    // ---- stage 1: indices (7 coalesced 64B wave-reads) ----
    int rows[7];
#pragma unroll
    for (int i = 0; i < 7; ++i) {
        const int kidx = i * 16 + g;
        rows[i] = idxp[kidx < KNEG ? kidx : (KNEG - 1)];
    }
    // ---- stage 2: all gathers in flight ----
    uint4 v[7];
#pragma unroll
    for (int i = 0; i < 7; ++i) {
        v[i] = gp[(size_t)rows[i] * 4 + c];
    }
    // query fragment: d in [16c, 16c+16) of row n
    const uint4 qw = gp[(size_t)n * 4 + c];
    float qf[16];
    dec4(qw.x, qf + 0); dec4(qw.y, qf + 4);
    dec4(qw.z, qf + 8); dec4(qw.w, qf + 12);

    // ---- stage 3: compute ----
    float acc = 0.f;
#pragma unroll
    for (int i = 0; i < 7; ++i) {
        float kf[16];
        dec4(v[i].x, kf + 0); dec4(v[i].y, kf + 4);
        dec4(v[i].z, kf + 8); dec4(v[i].w, kf + 12);
        float s0 = 0.f, s1 = 0.f;
#pragma unroll
        for (int j = 0; j < 8; ++j) {
            s0 = fmaf(kf[2 * j + 0], qf[2 * j + 0], s0);
            s1 = fmaf(kf[2 * j + 1], qf[2 * j + 1], s1);
        }
        float s = s0 + s1;
        s += __shfl_xor(s, 1);
        s += __shfl_xor(s, 2);     // 4-lane group holds full dot
        const float e = __expf(s); // TEMP == 1
        acc += (i * 16 + g < KNEG) ? e : 0.f;
    }
    // lanes within a group hold identical acc; butterfly across 16 groups
    acc += __shfl_xor(acc, 4);
    acc += __shfl_xor(acc, 8);
    acc += __shfl_xor(acc, 16);
    acc += __shfl_xor(acc, 32);

    if (l == 0) wpart[w] = log1pf(acc / pos[n]);   // log(p+neg)-log(p)
    __syncthreads();
    if (t == 0) {
        partials[blockIdx.x] = wpart[0] + wpart[1] + wpart[2] + wpart[3];
    }
}

// ---------------------------------------------------------------------------
// Kernel 3: reduce 6272 partials -> mean loss scalar.
// ---------------------------------------------------------------------------
__global__ __launch_bounds__(256) void k3_reduce(
    const float* __restrict__ partials, float* __restrict__ out)
{
    __shared__ float s[256];
    const int t = threadIdx.x;
    float a = 0.f;
    for (int i = t; i < NBLK2; i += 256) a += partials[i];
    s[t] = a;
    __syncthreads();
    for (int off = 128; off > 0; off >>= 1) {
        if (t < off) s[t] += s[t + off];
        __syncthreads();
    }
    if (t == 0) out[0] = s[0] * (1.0f / (float)BHW);
}

extern "C" void kernel_launch(void* const* d_in, const int* in_sizes, int n_in,
                              void* d_out, int out_size, void* d_ws, size_t ws_size,
                              hipStream_t stream)
{
    const float* x1  = (const float*)d_in[0];
    const float* x2  = (const float*)d_in[1];
    const int*   neg = (const int*)d_in[2];
    float* out = (float*)d_out;

    char* ws = (char*)d_ws;
    uint32_t* xq    = (uint32_t*)ws;                            // 25088*64 fp8 = 1.61 MB
    float* pos      = (float*)(ws + (size_t)BHW * DD);          // 25088 f32
    float* partials = (float*)(ws + (size_t)BHW * DD + BHW * 4);

    k1_normalize<<<8 * 49, 512, 0, stream>>>(x1, x2, xq, pos);
    k2_negative<<<NBLK2, 256, 0, stream>>>(xq, neg, pos, partials);
    k3_reduce<<<1, 256, 0, stream>>>(partials, out);
}

// Round 8
// 93.785 us; speedup vs baseline: 2.4141x; 1.0499x over previous
//
#include <hip/hip_runtime.h>

#define BHW   25088
#define HW    3136
#define DD    64
#define KNEG  100
#define NBLK2 (BHW / 4)   // 6272 blocks, 4 waves (n's) per block

#if __has_builtin(__builtin_amdgcn_sdot4)
#define HAVE_SDOT4 1
#else
#define HAVE_SDOT4 0
#endif

// int8 dot4: c += sum of signed-byte products (v_dot4_i32_i8 on gfx950)
__device__ __forceinline__ int dot4i8(uint32_t a, uint32_t b, int c) {
#if HAVE_SDOT4
    return __builtin_amdgcn_sdot4((int)a, (int)b, c, false);
#else
#pragma unroll
    for (int j = 0; j < 4; ++j) {
        c += (int)(int8_t)(a >> (8 * j)) * (int)(int8_t)(b >> (8 * j));
    }
    return c;
#endif
}

__device__ __forceinline__ uint32_t pack4i8(float a, float b, float c, float d) {
    const int ia = (int)rintf(a), ib = (int)rintf(b);
    const int ic = (int)rintf(c), id = (int)rintf(d);
    return (uint32_t)(ia & 0xff) | ((uint32_t)(ib & 0xff) << 8) |
           ((uint32_t)(ic & 0xff) << 16) | ((uint32_t)(id & 0xff) << 24);
}

// ---------------------------------------------------------------------------
// Kernel 1 (512 thr): normalize x1 rows -> xq (int8, q=round(127*x), row-major
// (n,64)), positive[n] in f32 (exact path). LDS tile-transpose; nontemporal
// input loads (single-use stream; keep L2 clean for the xq table).
// ---------------------------------------------------------------------------
__global__ __launch_bounds__(512) void k1_normalize(
    const float* __restrict__ x1, const float* __restrict__ x2,
    uint32_t* __restrict__ xq, float* __restrict__ pos)
{
    __shared__ float A[64][65];   // +1 pad
    __shared__ float C[64][65];
    __shared__ float inv1[64];

    const int t   = threadIdx.x;
    const int col = t & 63;       // hw within tile
    const int qr  = t >> 6;       // wave id 0..7
    const int b    = blockIdx.x / 49;
    const int tile = blockIdx.x % 49;
    const int hw0  = tile * 64;

    const float* p1 = x1 + (size_t)b * DD * HW + hw0;
    const float* p2 = x2 + (size_t)b * DD * HW + hw0;

#pragma unroll
    for (int i = 0; i < 8; ++i) {
        const int row = i * 8 + qr;                  // d index
        A[row][col] = __builtin_nontemporal_load(&p1[(size_t)row * HW + col]);
        C[row][col] = __builtin_nontemporal_load(&p2[(size_t)row * HW + col]);
    }
    __syncthreads();

    // phase 2: 512 threads = 64 rows x 8 d-chunks of 8 (8 lanes per row)
    const int l   = t & 63;
    const int r   = qr * 8 + (l >> 3);  // row (hw) within tile
    const int sub = l & 7;              // d-chunk 0..7

    float na = 0.f, nc = 0.f;
#pragma unroll
    for (int j = 0; j < 8; ++j) {
        const int d = sub * 8 + j;
        const float a = A[d][r], cc = C[d][r];
        na += a * a;
        nc += cc * cc;
    }
    na += __shfl_xor(na, 1); na += __shfl_xor(na, 2); na += __shfl_xor(na, 4);
    nc += __shfl_xor(nc, 1); nc += __shfl_xor(nc, 2); nc += __shfl_xor(nc, 4);
    const float r1 = 1.0f / fmaxf(sqrtf(na), 1e-12f);
    const float rc = 1.0f / fmaxf(sqrtf(nc), 1e-12f);
    const float scale = r1 * rc;

    float p = 0.f;
#pragma unroll
    for (int j = 0; j < 8; ++j) {
        const int d = sub * 8 + j;
        p += __expf(A[d][r] * C[d][r] * scale);   // TEMP == 1
    }
    p += __shfl_xor(p, 1); p += __shfl_xor(p, 2); p += __shfl_xor(p, 4);

    if (sub == 0) {
        pos[b * HW + hw0 + r] = p;
        inv1[r] = r1;
    }
    __syncthreads();

    // phase 3: write int8 table row-major: 64 rows x 16 uint (4 int8 each).
    uint32_t* outb = xq + (size_t)(b * HW + hw0) * 16;
    const int cp     = t & 15;    // uint index -> d = 4cp..4cp+3
    const int rowsel = t >> 4;    // 0..31
#pragma unroll
    for (int i = 0; i < 2; ++i) {
        const int nl = i * 32 + rowsel;
        const float s = inv1[nl] * 127.0f;
        outb[(size_t)nl * 16 + cp] =
            pack4i8(A[4 * cp + 0][nl] * s, A[4 * cp + 1][nl] * s,
                    A[4 * cp + 2][nl] * s, A[4 * cp + 3][nl] * s);
    }
}

// ---------------------------------------------------------------------------
// Kernel 2: negative[n] = sum_k exp(dot64(xq[n], xq[idx[n,k]]) / 127^2).
// One wave per n; 4 lanes per negative (g=l>>2), lane c=l&3 reads one uint4
// (16 int8 = quarter row); each gathered row = exactly one 64B line.
// Table 1.6MB -> fully L2-resident per XCD. int8 + v_dot4_i32_i8: 4 dot
// instrs per negative-lane vs ~24 VALU for the fp8 cvt+fma path.
// All 7 gathers issued back-to-back (MLP). NO fences (R3: acq/rel flushes
// per-XCD L2), NO grid-wide same-address atomics (R6: serialized RMW tail).
// ---------------------------------------------------------------------------
__global__ __launch_bounds__(256) void k2_negative(
    const uint32_t* __restrict__ xq, const int* __restrict__ neg_idx,
    const float* __restrict__ pos, float* __restrict__ partials)
{
    __shared__ float wpart[4];

    const int t = threadIdx.x;
    const int w = t >> 6;         // wave id 0..3
    const int l = t & 63;
    const int n = blockIdx.x * 4 + w;
    const int g = l >> 2;         // negative group 0..15
    const int c = l & 3;          // 16B slot within 64B row

    const uint4* gp = (const uint4*)xq;   // 4 x uint4 per row
    const int* idxp = neg_idx + (size_t)n * KNEG;

    // ---- stage 1: indices (7 coalesced wave-reads) ----
    int rows[7];
#pragma unroll
    for (int i = 0; i < 7; ++i) {
        const int kidx = i * 16 + g;
        rows[i] = idxp[kidx < KNEG ? kidx : (KNEG - 1)];
    }
    // ---- stage 2: all gathers in flight ----
    uint4 v[7];
#pragma unroll
    for (int i = 0; i < 7; ++i) {
        v[i] = gp[(size_t)rows[i] * 4 + c];
    }
    // query fragment: d in [16c,16c+16) of row n, already int8 -- no decode
    const uint4 qw = gp[(size_t)n * 4 + c];

    // ---- stage 3: compute ----
    const float inv1272 = 1.0f / 16129.0f;   // 1/127^2
    float acc = 0.f;
#pragma unroll
    for (int i = 0; i < 7; ++i) {
        int s = 0;
        s = dot4i8(v[i].x, qw.x, s);
        s = dot4i8(v[i].y, qw.y, s);
        s = dot4i8(v[i].z, qw.z, s);
        s = dot4i8(v[i].w, qw.w, s);
        s += __shfl_xor(s, 1);
        s += __shfl_xor(s, 2);     // 4-lane group holds full int dot
        const float e = __expf((float)s * inv1272);  // TEMP == 1
        acc += (i * 16 + g < KNEG) ? e : 0.f;
    }
    // lanes within a group hold identical acc; butterfly across 16 groups
    acc += __shfl_xor(acc, 4);
    acc += __shfl_xor(acc, 8);
    acc += __shfl_xor(acc, 16);
    acc += __shfl_xor(acc, 32);

    if (l == 0) wpart[w] = log1pf(acc / pos[n]);   // log(p+neg)-log(p)
    __syncthreads();
    if (t == 0) {
        partials[blockIdx.x] = wpart[0] + wpart[1] + wpart[2] + wpart[3];
    }
}

// ---------------------------------------------------------------------------
// Kernel 3: reduce 6272 partials -> mean loss scalar.
// ---------------------------------------------------------------------------
__global__ __launch_bounds__(256) void k3_reduce(
    const float* __restrict__ partials, float* __restrict__ out)
{
    __shared__ float s[256];
    const int t = threadIdx.x;
    float a = 0.f;
    for (int i = t; i < NBLK2; i += 256) a += partials[i];
    s[t] = a;
    __syncthreads();
    for (int off = 128; off > 0; off >>= 1) {
        if (t < off) s[t] += s[t + off];
        __syncthreads();
    }
    if (t == 0) out[0] = s[0] * (1.0f / (float)BHW);
}

extern "C" void kernel_launch(void* const* d_in, const int* in_sizes, int n_in,
                              void* d_out, int out_size, void* d_ws, size_t ws_size,
                              hipStream_t stream)
{
    const float* x1  = (const float*)d_in[0];
    const float* x2  = (const float*)d_in[1];
    const int*   neg = (const int*)d_in[2];
    float* out = (float*)d_out;

    char* ws = (char*)d_ws;
    uint32_t* xq    = (uint32_t*)ws;                            // 25088*64 int8 = 1.61 MB
    float* pos      = (float*)(ws + (size_t)BHW * DD);          // 25088 f32
    float* partials = (float*)(ws + (size_t)BHW * DD + BHW * 4);

    k1_normalize<<<8 * 49, 512, 0, stream>>>(x1, x2, xq, pos);
    k2_negative<<<NBLK2, 256, 0, stream>>>(xq, neg, pos, partials);
    k3_reduce<<<1, 256, 0, stream>>>(partials, out);
}